// Round 8
// baseline (6898.808 us; speedup 1.0000x reference)
//
#include <hip/hip_runtime.h>
#include <stdint.h>
#include <stddef.h>

// LSTM encoder, MI355X. 32 blocks x 16 batch rows x 512 threads (8 waves).
// Weights bf16, gate-scale folded (+/-log2e; g: 2log2e), packed as MFMA
// B-fragments in d_ws by prep_pack. All 10 weight K-chunks streamed L2->VGPR
// per step via asm global_load_dwordx4 + counted vmcnt (T3/T4); x activations
// loaded per-lane from global into A-fragments (no LDS staging, no
// loop-carried in-flight x register -> no phi-copy race, the r6 NaN cause).
// h staged bf16 in LDS; c fp32 in regs; EW parity-staggered across co-SIMD
// waves; setprio(1) around POST MFMAs (T5).

typedef float f32x4 __attribute__((ext_vector_type(4)));
typedef short s16x8 __attribute__((ext_vector_type(8)));

#define T_STEPS 1000
#define IN_DIM  64
#define HID     256
#define STRIDE  264           // LDS row (ushorts): h[0..255] + pad (528B, 16B-aligned)
#define THREADS 512
#define BT      16
#define LOG2E   1.44269504088896340736f

__device__ __forceinline__ unsigned int f2bf(float f) {
    union { float f; unsigned int u; } a; a.f = f;
    return (a.u + 0x7FFFu + ((a.u >> 16) & 1u)) >> 16;   // RNE bf16 bits
}
__device__ __forceinline__ float bf2f(unsigned short u) {
    union { float f; unsigned int u; } a; a.u = ((unsigned int)u) << 16;
    return a.f;
}

// ---------------- prep: pack scaled bf16 MFMA B-fragments -------------------
// frag fid = c*64 + w*8 + j  (c: K-chunk 0..9, w: wave, j = q*2+hp)
// lane (hi,l15) holds w[col][c*32+hi*8+e], col = q*256+w*32+hp*16+l15
__global__ void prep_pack(const float* __restrict__ w_ih,
                          const float* __restrict__ w_hh,
                          unsigned short* __restrict__ wpack) {
    const int lane = threadIdx.x;          // 64
    const int fid  = blockIdx.x;           // 640
    const int c  = fid >> 6;
    const int w  = (fid >> 3) & 7;
    const int j  = fid & 7;
    const int q  = j >> 1, hp = j & 1;
    const int l15 = lane & 15, hi = lane >> 4;
    const int col = (q << 8) | (w << 5) | (hp << 4) | l15;
    const int k0  = (c << 5) + (hi << 3);
    const float scale = (q == 2) ? (2.0f * LOG2E) : (-LOG2E);
    const float* src = (c < 8) ? (w_hh + (size_t)col * HID + k0)
                               : (w_ih + (size_t)col * IN_DIM + (k0 - HID));
    const f32x4 v0 = *reinterpret_cast<const f32x4*>(src);
    const f32x4 v1 = *reinterpret_cast<const f32x4*>(src + 4);
    s16x8 v;
    #pragma unroll
    for (int e = 0; e < 4; ++e) {
        v[e]     = (short)f2bf(scale * v0[e]);
        v[e + 4] = (short)f2bf(scale * v1[e]);
    }
    *reinterpret_cast<s16x8*>(wpack + (size_t)fid * 512 + lane * 8) = v;
}

// ---------------- fallback fragment build from f32 sources ------------------
__device__ __forceinline__ s16x8 raw_frag(const float* wh, const float* wi,
                                          int c, int w, int j, int hi, int l15) {
    const int q = j >> 1, hp = j & 1;
    const int col = (q << 8) | (w << 5) | (hp << 4) | l15;
    const int k0  = (c << 5) + (hi << 3);
    const float scale = (q == 2) ? (2.0f * LOG2E) : (-LOG2E);
    const float* src = (c < 8) ? (wh + (size_t)col * HID + k0)
                               : (wi + (size_t)col * IN_DIM + (k0 - HID));
    const f32x4 v0 = *reinterpret_cast<const f32x4*>(src);
    const f32x4 v1 = *reinterpret_cast<const f32x4*>(src + 4);
    s16x8 r;
    #pragma unroll
    for (int e = 0; e < 4; ++e) {
        r[e]     = (short)f2bf(scale * v0[e]);
        r[e + 4] = (short)f2bf(scale * v1[e]);
    }
    return r;
}

// asm-pinned 16B global load: dst <- [addr + IMM]
#define GL4(dst, addr, IMM) \
    asm volatile("global_load_dwordx4 %0, %1, off offset:" #IMM \
                 : "=v"(dst) : "v"(addr))

// counted vmem wait + scheduling fence (rule #18)
#define VMW(N) do { \
    asm volatile("s_waitcnt vmcnt(" #N ")" ::: "memory"); \
    __builtin_amdgcn_sched_barrier(0); } while (0)

// barrier that drains LDS ops but leaves VMEM loads in flight (T3/T4)
#define BAR() do { \
    __builtin_amdgcn_sched_barrier(0); \
    asm volatile("s_waitcnt lgkmcnt(0)\n\ts_barrier" ::: "memory"); \
    __builtin_amdgcn_sched_barrier(0); } while (0)

// ---------------- recurrent kernel ------------------------------------------
template<int RAW>
__global__ __launch_bounds__(THREADS, 2)
void lstm_rec(const float* __restrict__ x,
              const float* __restrict__ w_ih,
              const float* __restrict__ w_hh,
              const float* __restrict__ b_ih,
              const float* __restrict__ b_hh,
              const float* __restrict__ w_out,
              const float* __restrict__ b_out,
              const unsigned short* __restrict__ wpack,
              float* __restrict__ out)
{
    __shared__ __align__(16) unsigned short v_lds[BT][STRIDE];  // h, bf16

    const int tid  = threadIdx.x;
    const int lane = tid & 63;
    const int w    = tid >> 6;            // wave 0..7 -> owns 128 gate cols
    const int l15  = lane & 15;
    const int hi   = lane >> 4;
    const int b0   = blockIdx.x * BT;
    const int par  = (w ^ (w >> 2)) & 1;  // co-SIMD waves get opposite parity

    // ---- scaled biases (8 per lane, one per j)
    float bias[8];
    #pragma unroll
    for (int j = 0; j < 8; ++j) {
        const int q = j >> 1, hp = j & 1;
        const int col = (q << 8) | (w << 5) | (hp << 4) | l15;
        const float scale = (q == 2) ? (2.0f * LOG2E) : (-LOG2E);
        bias[j] = scale * (b_ih[col] + b_hh[col]);
    }

    // ---- zero h staging (h starts at 0)
    for (int i = tid; i < BT * STRIDE; i += THREADS)
        ((unsigned short*)v_lds)[i] = 0;
    __syncthreads();   // full drain: vmcnt == 0 past this point

    const unsigned short* aL = &v_lds[l15][0];   // A-frag row base (row=batch l15)
    // wave-frag byte base into wpack: fid = c*64 + w*8 + j -> byte fid*1024 + lane*16
    const uint64_t wb = (uint64_t)wpack + ((uint64_t)w << 13) + ((uint64_t)lane << 4);
    // x activation base for this lane: row b0+l15, t=T-1, elem hi*8 (bytes)
    uint64_t xaddr = (uint64_t)x
        + ((((uint64_t)(b0 + l15)) * T_STEPS + (T_STEPS - 1)) * IN_DIM + (hi << 3)) * 4;

    float cst[2][4];
    #pragma unroll
    for (int a_ = 0; a_ < 2; ++a_)
        #pragma unroll
        for (int r_ = 0; r_ < 4; ++r_) cst[a_][r_] = 0.0f;

#define AF(C) (*reinterpret_cast<const s16x8*>(aL + ((C) << 5) + (hi << 3)))

// issue one chunk's 8 fragment loads (asm path) or plain loads (RAW path)
#define LOADCHUNK(B, C) do {                                                    \
    if constexpr (RAW) {                                                        \
        _Pragma("unroll")                                                       \
        for (int j_ = 0; j_ < 8; ++j_) B[j_] = raw_frag(w_hh, w_ih, (C), w, j_, hi, l15); \
    } else {                                                                    \
        const uint64_t a0_ = wb + (uint64_t)((C) * 65536);                      \
        const uint64_t a1_ = a0_ + 4096;                                        \
        GL4(B[0], a0_, 0);    GL4(B[1], a0_, 1024);                             \
        GL4(B[2], a0_, 2048); GL4(B[3], a0_, 3072);                             \
        GL4(B[4], a1_, 0);    GL4(B[5], a1_, 1024);                             \
        GL4(B[6], a1_, 2048); GL4(B[7], a1_, 3072);                             \
    } } while (0)

// x activations for CURRENT step: chunk8 = elems hi*8.., chunk9 = +32 elems
#define XA_ISSUE do {                                                           \
    if constexpr (RAW) {                                                        \
        const float* xp_ = (const float*)xaddr;                                 \
        xa0 = *reinterpret_cast<const f32x4*>(xp_);                             \
        xa1 = *reinterpret_cast<const f32x4*>(xp_ + 4);                         \
        xa2 = *reinterpret_cast<const f32x4*>(xp_ + 32);                        \
        xa3 = *reinterpret_cast<const f32x4*>(xp_ + 36);                        \
    } else {                                                                    \
        GL4(xa0, xaddr, 0);   GL4(xa1, xaddr, 16);                              \
        GL4(xa2, xaddr, 128); GL4(xa3, xaddr, 144);                             \
    } } while (0)

#define CHUNK(AFV, BUF) do {                                                    \
    _Pragma("unroll")                                                           \
    for (int j_ = 0; j_ < 8; ++j_)                                              \
        acc[j_] = __builtin_amdgcn_mfma_f32_16x16x32_bf16(AFV, BUF[j_], acc[j_], 0, 0, 0); \
    } while (0)

#define POST(P) do {                                                            \
    __builtin_amdgcn_s_setprio(1);                                              \
    _Pragma("unroll")                                                           \
    for (int q_ = 0; q_ < 4; ++q_) {                                            \
        const int j_ = (q_ << 1) | (P);                                         \
        acc[j_] = __builtin_amdgcn_mfma_f32_16x16x32_bf16(a8, B0[j_], acc[j_], 0, 0, 0); \
        acc[j_] = __builtin_amdgcn_mfma_f32_16x16x32_bf16(a9, B1[j_], acc[j_], 0, 0, 0); \
    }                                                                           \
    __builtin_amdgcn_s_setprio(0); } while (0)

#define EW_PHASE(HP) do {                                                       \
    const int u_ = (w << 5) + ((HP) << 4) + l15;                                \
    _Pragma("unroll")                                                           \
    for (int r_ = 0; r_ < 4; ++r_) {                                            \
        const int b_ = (hi << 2) + r_;                                          \
        const float gi = acc[0 | (HP)][r_];                                     \
        const float gf = acc[2 | (HP)][r_];                                     \
        const float gg = acc[4 | (HP)][r_];                                     \
        const float go = acc[6 | (HP)][r_];                                     \
        const float si = __builtin_amdgcn_rcpf(1.0f + exp2f(gi));               \
        const float sf = __builtin_amdgcn_rcpf(1.0f + exp2f(gf));               \
        const float so = __builtin_amdgcn_rcpf(1.0f + exp2f(go));               \
        const float tg = 1.0f - 2.0f * __builtin_amdgcn_rcpf(exp2f(gg) + 1.0f); \
        float cc = cst[(HP)][r_];                                               \
        cc = sf * cc + si * tg;                                                 \
        cst[(HP)][r_] = cc;                                                     \
        const float tc = 1.0f - 2.0f * __builtin_amdgcn_rcpf(                   \
                             exp2f(2.0f * LOG2E * cc) + 1.0f);                  \
        v_lds[b_][u_] = (unsigned short)f2bf(so * tc);                          \
    } } while (0)

    f32x4 acc[8];
    s16x8 B0[8], B1[8];

    // prologue issue: queue = [c0(8), c1(8)] = 16 (same as steady state)
    LOADCHUNK(B0, 0);
    LOADCHUNK(B1, 1);

    #pragma unroll 1
    for (int s = 0; s < T_STEPS; ++s) {
        #pragma unroll
        for (int j = 0; j < 8; ++j) {
            f32x4 bb = {bias[j], bias[j], bias[j], bias[j]};
            acc[j] = bb;
        }
        s16x8 a0 = AF(0), a1 = AF(1);
        f32x4 xa0, xa1, xa2, xa3;
        // ledger (asm path): entry [c0,c1]=16; uniform VMW(8) x8
        VMW(8);  CHUNK(a0, B0); LOADCHUNK(B0, 2); s16x8 a2 = AF(2);
        VMW(8);  CHUNK(a1, B1); LOADCHUNK(B1, 3); s16x8 a3 = AF(3);
        VMW(8);  CHUNK(a2, B0); LOADCHUNK(B0, 4); s16x8 a4 = AF(4);
        VMW(8);  CHUNK(a3, B1); LOADCHUNK(B1, 5); s16x8 a5 = AF(5);
        VMW(8);  CHUNK(a4, B0); LOADCHUNK(B0, 6); s16x8 a6 = AF(6);
        VMW(8);  CHUNK(a5, B1); LOADCHUNK(B1, 7); s16x8 a7 = AF(7);
        VMW(8);  CHUNK(a6, B0); LOADCHUNK(B0, 8);
        VMW(8);  CHUNK(a7, B1); XA_ISSUE; LOADCHUNK(B1, 9);
        xaddr -= (uint64_t)(IN_DIM * 4);      // next step's t (value-only, no async state)
        // queue now [c8(8), xa(4), c9(8)] = 20
        VMW(12);               // c8 resident in B0

        BAR();                 // D: all h-reads (AF) done; EW h-writes may begin after
        VMW(8);                // xa resident
        s16x8 a8, a9;
        #pragma unroll
        for (int e = 0; e < 4; ++e) {
            a8[e]     = (short)f2bf(xa0[e]);
            a8[e + 4] = (short)f2bf(xa1[e]);
            a9[e]     = (short)f2bf(xa2[e]);
            a9[e + 4] = (short)f2bf(xa3[e]);
        }
        VMW(0);                // c9 resident in B1

        if (par == 0) { POST(0); EW_PHASE(0); POST(1); EW_PHASE(1); }
        else          { POST(1); EW_PHASE(1); POST(0); EW_PHASE(0); }

        // next-step weight prefetch into freed buffers (disjoint live ranges:
        // old B0/B1 died at POST -> coalesced across back-edge, no phi copy)
        __builtin_amdgcn_sched_barrier(0);
        LOADCHUNK(B0, 0);
        LOADCHUNK(B1, 1);
        BAR();                 // F: h(t+1) visible; prefetch stays in flight
    }

    // drain in-flight (dead) prefetch loads before their regs get reused
    asm volatile("s_waitcnt vmcnt(0)" ::: "memory");
    __builtin_amdgcn_sched_barrier(0);

    // ---- final projection: out[b][o] = h . w_out[o] + b_out[o]
    const int o  = tid & 127;
    const int bq = tid >> 7;  // 0..3
    #pragma unroll
    for (int rb = 0; rb < 4; ++rb) {
        const int b = bq + (rb << 2);
        float a = b_out[o];
        const float* wr = w_out + (size_t)o * HID;
        #pragma unroll 8
        for (int u = 0; u < HID; u += 4) {
            f32x4 wv = *reinterpret_cast<const f32x4*>(wr + u);
            a += wv[0] * bf2f(v_lds[b][u])     + wv[1] * bf2f(v_lds[b][u + 1])
               + wv[2] * bf2f(v_lds[b][u + 2]) + wv[3] * bf2f(v_lds[b][u + 3]);
        }
        out[(size_t)(b0 + b) * 128 + o] = a;
    }
#undef AF
#undef LOADCHUNK
#undef XA_ISSUE
#undef CHUNK
#undef POST
#undef EW_PHASE
}

extern "C" void kernel_launch(void* const* d_in, const int* in_sizes, int n_in,
                              void* d_out, int out_size, void* d_ws, size_t ws_size,
                              hipStream_t stream) {
    const float* x     = (const float*)d_in[0];
    const float* w_ih  = (const float*)d_in[1];
    const float* w_hh  = (const float*)d_in[2];
    const float* b_ih  = (const float*)d_in[3];
    const float* b_hh  = (const float*)d_in[4];
    const float* w_out = (const float*)d_in[5];
    const float* b_out = (const float*)d_in[6];
    float* out = (float*)d_out;

    const bool pack = (ws_size >= (size_t)(640 * 1024));
    if (pack) {
        unsigned short* wpack = (unsigned short*)d_ws;
        hipLaunchKernelGGL(prep_pack, dim3(640), dim3(64), 0, stream, w_ih, w_hh, wpack);
        hipLaunchKernelGGL((lstm_rec<0>), dim3(512 / BT), dim3(THREADS), 0, stream,
                           x, w_ih, w_hh, b_ih, b_hh, w_out, b_out,
                           (const unsigned short*)wpack, out);
    } else {
        hipLaunchKernelGGL((lstm_rec<1>), dim3(512 / BT), dim3(THREADS), 0, stream,
                           x, w_ih, w_hh, b_ih, b_hh, w_out, b_out,
                           (const unsigned short*)nullptr, out);
    }
}